// Round 18
// baseline (157.440 us; speedup 1.0000x reference)
//
#include <hip/hip_runtime.h>

#define LSEQ 512
#define NB 64
#define NCHUNK 51  // 16*51 = 816 >= 512 + 3*80 + 63 = 815 steps

// lanes 1..63 <- x[lane-1]; lane 0 <- old[0] (wave_shr:1, bound_ctrl=0).
__device__ __forceinline__ float dpp_shr1(float old, float x) {
  return __int_as_float(__builtin_amdgcn_update_dpp(
      __float_as_int(old), __float_as_int(x), 0x138, 0xF, 0xF, false));
}
// lane l <- lane l+1 (wave_shl:1) — rotates injection registers.
__device__ __forceinline__ float dpp_shl1(float x) {
  return __int_as_float(__builtin_amdgcn_update_dpp(
      0, __float_as_int(x), 0x130, 0xF, 0xF, false));
}

// (d,e) pair encodes v = d - log2(e); exact softmin, log deferred to the end.
__device__ __forceinline__ void renorm(float& d, float& e) {
  const int eb = __float_as_int(e);
  const int E = (eb >> 23) - 127;
  e = __int_as_float((eb & 0x007FFFFF) | 0x3F800000);
  d -= (float)E;
}

// Per-batch DP state (SROA-decomposed into registers).
struct St {
  float v0d, v0e, v1d, v1e;  // R'[i0][j-1], R'[i1][j-1] pairs
  float r0d, r0e;            // R'[i0-1][j-1] pair
  float tcur;                // target'[j-1]
  float p0, p1;              // pred'[i0-1], pred'[i1-1]
};

// One 16-step chunk, 2 rows/lane, TWO INDEPENDENT BATCHES per wave (A,B).
// R13-R17 showed per-step wall ~253cy is invariant under intra-wave
// scheduling: 1 wave/SIMD exposes all dependent latency (issue ~105cy, wall
// 253cy, VALUBusy(active) 44%). The B-stream is the missing independent work:
// its instructions fill A's stall cycles inside the same wave.
template <bool FULL>
__device__ __forceinline__ void step_one(int cbase, int u, const float* tg,
                                         const float2* ring2P, St& s,
                                         float& tinj, float& rdinj,
                                         float& reinj, int lane, float& outd,
                                         float& oute) {
  s.tcur = dpp_shr1(tinj, s.tcur);
  const float r1d = dpp_shr1(rdinj, s.v1d);
  const float r1e = dpp_shr1(reinj, s.v1e);
  if (u < 15) {
    tinj = dpp_shl1(tinj);
    rdinj = dpp_shl1(rdinj);
    reinj = dpp_shl1(reinj);
  }
  const float diff0 = s.p0 - s.tcur;
  const float M0 = fminf(fminf(s.r0d, r1d), s.v0d);
  const float d0 = __builtin_fmaf(diff0, diff0, M0);
  const float diff1 = s.p1 - s.tcur;
  const float M1 = fminf(fminf(s.v0d, d0), s.v1d);
  const float d1 = __builtin_fmaf(diff1, diff1, M1);
  const float x0 = __builtin_amdgcn_exp2f(M0 - s.r0d);
  const float x1 = __builtin_amdgcn_exp2f(M0 - r1d);
  const float x2 = __builtin_amdgcn_exp2f(M0 - s.v0d);
  const float x3 = __builtin_amdgcn_exp2f(M1 - s.v0d);
  const float x4 = __builtin_amdgcn_exp2f(M1 - d0);
  const float x5 = __builtin_amdgcn_exp2f(M1 - s.v1d);
  const float e0 = __builtin_fmaf(x2, s.v0e, __builtin_fmaf(x1, r1e, x0 * s.r0e));
  const float e1 = __builtin_fmaf(x5, s.v1e, __builtin_fmaf(x4, e0, x3 * s.v0e));
  outd = d1;
  oute = e1;
  if (FULL) {
    s.v0d = d0; s.v0e = e0; s.v1d = d1; s.v1e = e1;
  } else {
    const int j = cbase + 1 + u - lane;
    const bool act = ((unsigned)(j - 1)) < (unsigned)LSEQ;
    s.v0d = act ? d0 : s.v0d; s.v0e = act ? e0 : s.v0e;
    s.v1d = act ? d1 : s.v1d; s.v1e = act ? e1 : s.v1e;
  }
  s.r0d = r1d;
  s.r0e = r1e;
}

template <bool FULL>
__device__ __forceinline__ void chunk16(
    int cbase, const float* tgA, const float* tgB, const float2* ringPA,
    float2* ringWA, const float2* ringPB, float2* ringWB, bool is_wr, int lane,
    St& A, St& B) {
  renorm(A.v0d, A.v0e); renorm(A.v1d, A.v1e);
  renorm(B.v0d, B.v0e); renorm(B.v1d, B.v1e);

  float tinjA = tgA[(cbase + (lane & 15)) & 511];
  const float2 rjA = ringPA[(cbase + 1 + (lane & 15)) & 127];
  float rdinjA = rjA.x, reinjA = rjA.y;
  float tinjB = tgB[(cbase + (lane & 15)) & 511];
  const float2 rjB = ringPB[(cbase + 1 + (lane & 15)) & 127];
  float rdinjB = rjB.x, reinjB = rjB.y;

  float vvdA[16], vveA[16], vvdB[16], vveB[16];
#pragma unroll
  for (int u = 0; u < 16; ++u) {
    step_one<FULL>(cbase, u, tgA, ringPA, A, tinjA, rdinjA, reinjA, lane,
                   vvdA[u], vveA[u]);
    step_one<FULL>(cbase, u, tgB, ringPB, B, tinjB, rdinjB, reinjB, lane,
                   vvdB[u], vveB[u]);
  }

  if (is_wr) {  // lane 63 publishes row 128(w+1) for both batches
    const int j0 = cbase - 62;
#pragma unroll
    for (int k = 0; k < 16; ++k) {
      if (FULL || (((unsigned)(j0 + k - 1)) < (unsigned)LSEQ)) {
        ringWA[(j0 + k) & 127] = make_float2(vvdA[k], vveA[k]);
        ringWB[(j0 + k) & 127] = make_float2(vvdB[k], vveB[k]);
      }
    }
  }
}

// Soft-DTW banded wavefront: one block per TWO batches, 4 waves x 64 lanes x
// 2 rows x 2 batches. Per batch identical to R13 (proven): lane l of wave w
// owns rows 128w+2l+1,+2; column j = s-80w-l; LDS float2 ring + barrier every
// 16 steps; ring write/read separated by the top-of-chunk barrier; concurrent
// writes land +18..+33 past the read window (disjoint mod 128).
__global__ __launch_bounds__(256) void dtw_band(
    const float* __restrict__ pred, const float* __restrict__ target,
    float* __restrict__ part) {
  const int b = blockIdx.x;  // handles batches 2b, 2b+1
  const int tid = threadIdx.x;
  const int w = tid >> 6;
  const int lane = tid & 63;
  const bool is_wr = (lane == 63) && (w < 3);

  __shared__ float tgA[LSEQ], tgB[LSEQ];
  __shared__ float2 ringsA[4][128], ringsB[4][128];  // row 3: INF dummy

  const float SC = 3.79828146f;  // sqrt(C1), C1 = (1/g)*log2(e), g = 0.1
  St A, B;
  {
    const float2 ppA = ((const float2*)(pred + (2 * b) * LSEQ))[tid];
    A.p0 = ppA.x * SC; A.p1 = ppA.y * SC;
    const float2 ttA = ((const float2*)(target + (2 * b) * LSEQ))[tid];
    ((float2*)tgA)[tid] = make_float2(ttA.x * SC, ttA.y * SC);
    const float2 ppB = ((const float2*)(pred + (2 * b + 1) * LSEQ))[tid];
    B.p0 = ppB.x * SC; B.p1 = ppB.y * SC;
    const float2 ttB = ((const float2*)(target + (2 * b + 1) * LSEQ))[tid];
    ((float2*)tgB)[tid] = make_float2(ttB.x * SC, ttB.y * SC);
    ((float2*)ringsA)[tid] = make_float2(INFINITY, 1.0f);
    ((float2*)ringsA)[tid + 256] = make_float2(INFINITY, 1.0f);
    ((float2*)ringsB)[tid] = make_float2(INFINITY, 1.0f);
    ((float2*)ringsB)[tid + 256] = make_float2(INFINITY, 1.0f);
  }

  const int lag = w * 80;
  const int cw0 = 5 * w;  // wave-active chunks: [cw0, cw0+35]
  const float2* __restrict__ ringPA = ringsA[w == 0 ? 3 : w - 1];
  float2* __restrict__ ringWA = ringsA[w];
  const float2* __restrict__ ringPB = ringsB[w == 0 ? 3 : w - 1];
  float2* __restrict__ ringWB = ringsB[w];

  A.v0d = INFINITY; A.v0e = 1.0f; A.v1d = INFINITY; A.v1e = 1.0f;
  A.r0d = (tid == 0) ? 0.0f : INFINITY; A.r0e = 1.0f; A.tcur = 0.0f;
  B.v0d = INFINITY; B.v0e = 1.0f; B.v1d = INFINITY; B.v1e = 1.0f;
  B.r0d = (tid == 0) ? 0.0f : INFINITY; B.r0e = 1.0f; B.tcur = 0.0f;

  for (int c = 0; c < NCHUNK; ++c) {
    __syncthreads();  // top of chunk c (also orders init writes at c=0)
    if (c < cw0 || c > cw0 + 35) continue;  // wave-uniform
    const int cbase = 16 * c - lag;
    if (c >= cw0 + 4 && c <= cw0 + 31)
      chunk16<true>(cbase, tgA, tgB, ringPA, ringWA, ringPB, ringWB, is_wr,
                    lane, A, B);
    else
      chunk16<false>(cbase, tgA, tgB, ringPA, ringWA, ringPB, ringWB, is_wr,
                     lane, A, B);
  }

  if (tid == 255) {  // row 512 = wave 3 lane 63 i1; unscale by 1/C1 = g*ln2
    part[2 * b] = (A.v1d - __builtin_amdgcn_logf(A.v1e)) * 0.069314718f;
    part[2 * b + 1] = (B.v1d - __builtin_amdgcn_logf(B.v1e)) * 0.069314718f;
  }
}

__global__ void dtw_reduce(const float* __restrict__ part,
                           float* __restrict__ out) {
  float v = part[threadIdx.x];
#pragma unroll
  for (int o = 32; o > 0; o >>= 1) v += __shfl_down(v, o);
  if (threadIdx.x == 0) out[0] = v * (1.0f / NB);
}

extern "C" void kernel_launch(void* const* d_in, const int* in_sizes, int n_in,
                              void* d_out, int out_size, void* d_ws,
                              size_t ws_size, hipStream_t stream) {
  const float* pred = (const float*)d_in[0];
  const float* target = (const float*)d_in[1];
  float* part = (float*)d_ws;

  dtw_band<<<NB / 2, 256, 0, stream>>>(pred, target, part);
  dtw_reduce<<<1, 64, 0, stream>>>(part, (float*)d_out);
}

// Round 21
// 89.363 us; speedup vs baseline: 1.7618x; 1.7618x over previous
//
#include <hip/hip_runtime.h>

#define LSEQ 512
#define NB 64
#define NCHUNK 51  // 16*51 = 816 >= 512 + 3*80 + 63 = 815 steps

// lanes 1..63 <- x[lane-1]; lane 0 <- old[0] (wave_shr:1, bound_ctrl=0).
// CRITICAL: the injection select MUST be fused into the old operand, not a
// lane-varying ternary around the DPP. A ternary lets the compiler execute
// v_mov_b32_dpp with exec = {lanes 1..63}; GFX9 DPP treats exec-disabled
// SOURCE lanes as invalid, so lane 1 (sourcing lane 0) silently gets old/0.
// Evidence: R12/R19/R20 (ternary) all fail with value-collapse; R13-R18
// (fused old) all pass. This is the session's most expensive lesson.
__device__ __forceinline__ float dpp_shr1_inj(float inj, float x) {
  return __int_as_float(__builtin_amdgcn_update_dpp(
      __float_as_int(inj), __float_as_int(x), 0x138, 0xF, 0xF, false));
}

__device__ __forceinline__ float rdlane(float x, int u) {
  return __int_as_float(__builtin_amdgcn_readlane(__float_as_int(x), u));
}

// (d,e) pair encodes v = d - log2(e); exact softmin, log deferred to the end.
__device__ __forceinline__ void renorm(float& d, float& e) {
  const int eb = __float_as_int(e);
  const int E = (eb >> 23) - 127;
  e = __int_as_float((eb & 0x007FFFFF) | 0x3F800000);
  d -= (float)E;
}

// One 16-step chunk, 2 rows/lane. vs R13: target values in 16 per-lane
// registers (loaded at chunk top; no cross-lane movement for t at all), ring
// injection from SGPRs via readlane (no per-step rotations). Cross-lane ops
// per step: 6 -> 2 (both with the injection fused in the old operand).
template <bool FULL>
__device__ __forceinline__ void chunk16(
    int cbase, const float* tgpad, const float2* ring2P, float2* ring2W,
    float p0, float p1, bool is_wr, int lane, float& v0d, float& v0e,
    float& v1d, float& v1e, float& r0d, float& r0e) {
  renorm(v0d, v0e);
  renorm(v1d, v1e);

  // per-lane target registers for this chunk: tt[u] = tg'[cbase+u-lane]
  float tt[16];
  const int tb = 64 + cbase - lane;  // front pad 64 keeps index >= 1
#pragma unroll
  for (int k = 0; k < 16; ++k) tt[k] = tgpad[tb + k];

  // ring injection -> SGPRs: lane k (k<16) holds slot cbase+1+k
  const float2 rj = ring2P[(cbase + 1 + (lane & 15)) & 127];
  float sjd[16], sje[16];
#pragma unroll
  for (int k = 0; k < 16; ++k) {
    sjd[k] = rdlane(rj.x, k);
    sje[k] = rdlane(rj.y, k);
  }

  float vvd[16], vve[16];
#pragma unroll
  for (int u = 0; u < 16; ++u) {
    // R'[i0-1][j] pair: lanes 1..63 from lane-1's v1; lane 0 from ring SGPR
    const float r1d = dpp_shr1_inj(sjd[u], v1d);
    const float r1e = dpp_shr1_inj(sje[u], v1e);
    const float tcu = tt[u];  // target'[j-1], register-resident
    // cell0 (row i0): diag (r0d,r0e), up (r1d,r1e), left (v0d,v0e)
    const float diff0 = p0 - tcu;
    const float M0 = fminf(fminf(r0d, r1d), v0d);
    const float d0 = __builtin_fmaf(diff0, diff0, M0);
    // cell1 (row i1): diag (v0d,v0e)_old, up (d0,e0), left (v1d,v1e)
    const float diff1 = p1 - tcu;
    const float M1 = fminf(fminf(v0d, d0), v1d);
    const float d1 = __builtin_fmaf(diff1, diff1, M1);
    const float x0 = __builtin_amdgcn_exp2f(M0 - r0d);
    const float x1 = __builtin_amdgcn_exp2f(M0 - r1d);
    const float x2 = __builtin_amdgcn_exp2f(M0 - v0d);
    const float x3 = __builtin_amdgcn_exp2f(M1 - v0d);
    const float x4 = __builtin_amdgcn_exp2f(M1 - d0);
    const float x5 = __builtin_amdgcn_exp2f(M1 - v1d);
    const float e0 = __builtin_fmaf(x2, v0e, __builtin_fmaf(x1, r1e, x0 * r0e));
    const float e1 = __builtin_fmaf(x5, v1e, __builtin_fmaf(x4, e0, x3 * v0e));
    vvd[u] = d1;
    vve[u] = e1;
    if (FULL) {
      v0d = d0; v0e = e0; v1d = d1; v1e = e1;
    } else {
      const int j = cbase + 1 + u - lane;
      const bool act = ((unsigned)(j - 1)) < (unsigned)LSEQ;
      v0d = act ? d0 : v0d; v0e = act ? e0 : v0e;  // inactive lanes keep
      v1d = act ? d1 : v1d; v1e = act ? e1 : v1e;  // (INF,1); NaN discarded
    }
    r0d = r1d;
    r0e = r1e;
  }

  if (is_wr) {  // lane 63 publishes row 128(w+1) = its i1
    const int j0 = cbase - 62;
#pragma unroll
    for (int k = 0; k < 16; ++k) {
      if (FULL || (((unsigned)(j0 + k - 1)) < (unsigned)LSEQ))
        ring2W[(j0 + k) & 127] = make_float2(vvd[k], vve[k]);
    }
  }
}

// Soft-DTW banded wavefront, one block per batch, 4 waves x 64 lanes x 2 rows.
// Lane l of wave w owns rows 128w+2l+1, +2; column j = s - 80w - l at step s.
// Ring (lag=80): entry col J read by wave w at top of chunk c was written by
// wave w-1 in its chunk c-1, burst before the top-of-c barrier; concurrent
// writes land +18..+33 past the read window (disjoint mod 128).
__global__ __launch_bounds__(256) void dtw_band(
    const float* __restrict__ pred, const float* __restrict__ target,
    float* __restrict__ part) {
  const int b = blockIdx.x;
  const int tid = threadIdx.x;  // 0..255
  const int w = tid >> 6;
  const int lane = tid & 63;
  const bool is_wr = (lane == 63) && (w < 3);

  __shared__ float tgpad[640];       // [64 pad][512 data][64 pad]
  __shared__ float2 rings2[4][128];  // rows 0..2: interfaces; row 3: INF dummy

  const float SC = 3.79828146f;  // sqrt(C1), C1 = (1/g)*log2(e), g = 0.1
  const float2 pp = ((const float2*)(pred + b * LSEQ))[tid];
  const float p0 = pp.x * SC, p1 = pp.y * SC;  // rows 2*tid+1, 2*tid+2
  const float2 tt = ((const float2*)(target + b * LSEQ))[tid];
  ((float2*)(tgpad + 64))[tid] = make_float2(tt.x * SC, tt.y * SC);
  if (tid < 64) {
    tgpad[tid] = 0.0f;        // pads: read only by inactive cells
    tgpad[576 + tid] = 0.0f;
  }
  ((float2*)rings2)[tid] = make_float2(INFINITY, 1.0f);
  ((float2*)rings2)[tid + 256] = make_float2(INFINITY, 1.0f);

  const int lag = w * 80;
  const int cw0 = 5 * w;  // wave-active chunks: [cw0, cw0+35]
  const float2* __restrict__ ring2P = rings2[w == 0 ? 3 : w - 1];
  float2* __restrict__ ring2W = rings2[w];

  float v0d = INFINITY, v0e = 1.0f;          // R'[i0][j-1]
  float v1d = INFINITY, v1e = 1.0f;          // R'[i1][j-1]
  float r0d = (tid == 0) ? 0.0f : INFINITY;  // R'[i0-1][j-1]; seed R'[0][0]
  float r0e = 1.0f;

  for (int c = 0; c < NCHUNK; ++c) {
    __syncthreads();  // top of chunk c (also orders init writes at c=0)
    if (c < cw0 || c > cw0 + 35) continue;  // wave-uniform
    const int cbase = 16 * c - lag;
    if (c >= cw0 + 4 && c <= cw0 + 31)
      chunk16<true>(cbase, tgpad, ring2P, ring2W, p0, p1, is_wr, lane, v0d,
                    v0e, v1d, v1e, r0d, r0e);
    else
      chunk16<false>(cbase, tgpad, ring2P, ring2W, p0, p1, is_wr, lane, v0d,
                     v0e, v1d, v1e, r0d, r0e);
  }

  if (tid == 255)  // row 512 = wave 3 lane 63 i1; unscale by 1/C1 = g*ln2
    part[b] = (v1d - __builtin_amdgcn_logf(v1e)) * 0.069314718f;
}

__global__ void dtw_reduce(const float* __restrict__ part,
                           float* __restrict__ out) {
  float v = part[threadIdx.x];
#pragma unroll
  for (int o = 32; o > 0; o >>= 1) v += __shfl_down(v, o);
  if (threadIdx.x == 0) out[0] = v * (1.0f / NB);
}

extern "C" void kernel_launch(void* const* d_in, const int* in_sizes, int n_in,
                              void* d_out, int out_size, void* d_ws,
                              size_t ws_size, hipStream_t stream) {
  const float* pred = (const float*)d_in[0];
  const float* target = (const float*)d_in[1];
  float* part = (float*)d_ws;

  dtw_band<<<NB, 256, 0, stream>>>(pred, target, part);
  dtw_reduce<<<1, 64, 0, stream>>>(part, (float*)d_out);
}